// Round 5
// baseline (119.336 us; speedup 1.0000x reference)
//
#include <hip/hip_runtime.h>
#include <math.h>

// Problem constants (from reference)
#define B 4
#define H 2
#define L 2048
#define DM 32          // d_model
#define F 16           // feat dim
#define HD 16          // head dim
#define DD 273         // 1 + F + F*F taylor feature dim
#define CHK 64         // chunk length
#define NC (L / CHK)   // 32 chunks
#define BH (B * H)     // 8

#define SC_LIN 0.5f                   // 1/RRD, RRD=2
#define SC_QUAD 0.17677669529663687f  // 1/(RD*sqrt(2)) = 1/(4*sqrt(2))

// ---------------------------------------------------------------------------
// Kernel 1: fused projection + per-chunk state sums (round-3-proven).
// Block = (bh, ch), 256 threads. Phase 1: project q,k,v for this chunk's 64
// rows (head h only, 48 channels; lane = row, wave picks 12 channels); write
// q,k,v to global, keep k,v in LDS. Phase 2: thread dd computes S_kv[dd][:]
// and S_k[dd] over the 64 positions (k divergent LDS, v broadcast float4).
// ---------------------------------------------------------------------------
__global__ __launch_bounds__(256) void chunksum_kernel(
    const float* __restrict__ hs, const float* __restrict__ Wq,
    const float* __restrict__ Wk, const float* __restrict__ Wv,
    float* __restrict__ qp, float* __restrict__ kp, float* __restrict__ vp,
    float* __restrict__ S_kv, float* __restrict__ S_k) {
  int blk = blockIdx.x;  // bh*NC + ch
  int bh = blk >> 5, ch = blk & (NC - 1);
  int b = bh >> 1, h = bh & 1;
  int lane = threadIdx.x & 63, wave = threadIdx.x >> 6;
  int l = ch * CHK + lane;

  __shared__ float ks[CHK][F + 1];  // padded; col 16 = 1.0 sentinel
  __shared__ float vs[CHK][F];

  // ---- phase 1: projection, x row in registers
  float x[DM];
  const float4* xr = (const float4*)(hs + ((size_t)b * L + l) * DM);
#pragma unroll
  for (int j = 0; j < DM / 4; j++) {
    float4 v = xr[j];
    x[4 * j] = v.x; x[4 * j + 1] = v.y; x[4 * j + 2] = v.z; x[4 * j + 3] = v.w;
  }
  for (int c = wave * 12; c < wave * 12 + 12; c++) {
    int kind = c >> 4;  // 0=q, 1=k, 2=v (uniform per iteration)
    int f = c & 15;
    const float* __restrict__ W = (kind == 0) ? Wq : (kind == 1) ? Wk : Wv;
    const float* wr = W + (size_t)(h * 16 + f) * DM;
    float acc = 0.f;
#pragma unroll
    for (int i = 0; i < DM; i++) acc += x[i] * wr[i];
    float* dst = (kind == 0) ? qp : (kind == 1) ? kp : vp;
    dst[((size_t)bh * L + l) * F + f] = acc;
    if (kind == 1) ks[lane][f] = acc;
    if (kind == 2) vs[lane][f] = acc;
  }
  if (threadIdx.x < CHK) ks[threadIdx.x][16] = 1.0f;
  __syncthreads();

  // ---- phase 2: per-dd sums
#pragma unroll
  for (int rep = 0; rep < 2; rep++) {
    int dd = threadIdx.x + rep * 256;
    if (dd >= DD) break;
    int i, j;
    float sc;
    if (dd == 0) {
      i = 16; j = 16; sc = 1.0f;
    } else if (dd <= F) {
      i = dd - 1; j = 16; sc = SC_LIN;
    } else {
      int m = dd - 17;
      i = m >> 4; j = m & 15; sc = SC_QUAD;
    }
    float acc[HD];
#pragma unroll
    for (int hh = 0; hh < HD; hh++) acc[hh] = 0.f;
    float acck = 0.f;
    for (int p = 0; p < CHK; p++) {
      float kf = sc * ks[p][i] * ks[p][j];
      acck += kf;
      const float4* vr = (const float4*)vs[p];  // broadcast (uniform p)
#pragma unroll
      for (int h4 = 0; h4 < 4; h4++) {
        float4 v = vr[h4];
        acc[4 * h4] += kf * v.x;
        acc[4 * h4 + 1] += kf * v.y;
        acc[4 * h4 + 2] += kf * v.z;
        acc[4 * h4 + 3] += kf * v.w;
      }
    }
    float* dst = S_kv + ((size_t)blk * DD + dd) * HD;
#pragma unroll
    for (int hh = 0; hh < HD; hh++) dst[hh] = acc[hh];
    S_k[(size_t)blk * DD + dd] = acck;
  }
}

// ---------------------------------------------------------------------------
// Kernel 2: element-parallel exclusive prefix over NC chunks per (b,h).
// ---------------------------------------------------------------------------
#define PSLICES 19  // ceil((DD*HD + DD)/256)
__global__ __launch_bounds__(256) void prefix_kernel(float* __restrict__ S_kv,
                                                     float* __restrict__ S_k) {
  int blk = blockIdx.x;
  int bh = blk / PSLICES, sl = blk % PSLICES;
  int e = sl * 256 + threadIdx.x;
  if (e < DD * HD) {
    size_t base = (size_t)bh * NC * DD * HD + e;
    float v[NC];
#pragma unroll
    for (int c = 0; c < NC; c++) v[c] = S_kv[base + (size_t)c * DD * HD];
    float run = 0.f;
#pragma unroll
    for (int c = 0; c < NC; c++) {
      S_kv[base + (size_t)c * DD * HD] = run;
      run += v[c];
    }
  } else if (e < DD * HD + DD) {
    int e2 = e - DD * HD;
    size_t base = (size_t)bh * NC * DD + e2;
    float v[NC];
#pragma unroll
    for (int c = 0; c < NC; c++) v[c] = S_k[base + (size_t)c * DD];
    float run = 0.f;
#pragma unroll
    for (int c = 0; c < NC; c++) {
      S_k[base + (size_t)c * DD] = run;
      run += v[c];
    }
  }
}

// ---------------------------------------------------------------------------
// Kernel 3: fused per-chunk output + Wo projection.
// Block = (b, ch), 512 threads = 8 waves. Waves 0-3: head 0, split u=wave;
// waves 4-7: head 1, split u=wave-4. lane = position t. Inter: dd = u+4m
// (wave-uniform -> scalar loads of prefixed state). Intra: s = u+4m, masked,
// closed-form score, k/v rows wave-uniform. 4-way reduce per (h,t) -> y in
// LDS -> apply 32x32 Wo in-block (Wo rows uniform; ys stride-33 reads are
// bank-conflict-free). No y round-trip, no 5th kernel.
// ---------------------------------------------------------------------------
__global__ __launch_bounds__(512) void outchunk_kernel(
    const float* __restrict__ qp, const float* __restrict__ kp,
    const float* __restrict__ vp, const float* __restrict__ St_kv,
    const float* __restrict__ St_k, const float* __restrict__ Wo,
    float* __restrict__ out) {
  int blk = blockIdx.x;  // b*NC + ch
  int b = blk >> 5, ch = blk & (NC - 1);
  int t = threadIdx.x & 63;
  int wave = __builtin_amdgcn_readfirstlane(threadIdx.x >> 6);  // 0..7
  int h = wave >> 2;  // head (uniform)
  int u = wave & 3;   // work-split (uniform)
  int bh = b * H + h;
  int sblk = bh * NC + ch;

  __shared__ float qs[2][CHK][F + 1];  // padded, col 16 = 1.0
  __shared__ float red[8][CHK][21];    // odd stride -> conflict-free
  __shared__ float ys[CHK][DM + 1];    // y for both heads, stride 33

  // stage q for both heads: 2*64*16 floats = 512 float4, one per thread
  {
    int i = threadIdx.x;
    int h2 = i >> 8, r = (i >> 2) & 63, c4 = (i & 3) * 4;
    const float4* qb =
        (const float4*)(qp + ((size_t)(b * H + h2) * L + (size_t)ch * CHK) * F);
    float4 v = qb[i & 255];
    qs[h2][r][c4] = v.x; qs[h2][r][c4 + 1] = v.y;
    qs[h2][r][c4 + 2] = v.z; qs[h2][r][c4 + 3] = v.w;
    if (i < 2 * CHK) qs[i >> 6][i & 63][16] = 1.0f;
  }

  // q row for this lane's (head, position), in registers
  float qreg[F];
  const float4* qrow =
      (const float4*)(qp + ((size_t)bh * L + (size_t)ch * CHK + t) * F);
#pragma unroll
  for (int j = 0; j < 4; j++) {
    float4 v = qrow[j];
    qreg[4 * j] = v.x; qreg[4 * j + 1] = v.y;
    qreg[4 * j + 2] = v.z; qreg[4 * j + 3] = v.w;
  }
  __syncthreads();

  float acc[HD];
#pragma unroll
  for (int hh = 0; hh < HD; hh++) acc[hh] = 0.f;
  float den = 0.f;

  const float* __restrict__ Sbase = St_kv + (size_t)sblk * DD * HD;
  const float* __restrict__ Skb = St_k + (size_t)sblk * DD;

  // ---- inter-chunk: dd = u + 4m (uniform per wave -> scalar loads)
  for (int m = 0; m < 69; m++) {
    int dd = u + (m << 2);
    if (dd >= DD) break;  // wave-uniform guard
    float phi;
    if (dd == 0) {
      phi = 1.0f;
    } else if (dd <= F) {
      phi = qs[h][t][dd - 1] * SC_LIN;
    } else {
      int mm = dd - 17;
      phi = qs[h][t][mm >> 4] * qs[h][t][mm & 15] * SC_QUAD;
    }
    den += phi * Skb[dd];
    const float* __restrict__ Sr = Sbase + dd * HD;  // uniform
#pragma unroll
    for (int jj = 0; jj < HD; jj++) acc[jj] += phi * Sr[jj];
  }

  // ---- intra-chunk causal: s = u + 4m, closed-form score, masked
  const float* __restrict__ kbase =
      kp + ((size_t)bh * L + (size_t)ch * CHK) * F;
  const float* __restrict__ vbase =
      vp + ((size_t)bh * L + (size_t)ch * CHK) * F;
#pragma unroll
  for (int mm = 0; mm < CHK / 4; mm++) {
    int s = u + mm * 4;
    const float* __restrict__ kr = kbase + s * F;  // uniform
    float dot = 0.f;
#pragma unroll
    for (int i = 0; i < F; i++) dot += qreg[i] * kr[i];
    float scv = 1.0f + dot * 0.25f + dot * dot * 0.03125f;
    scv = (s <= t) ? scv : 0.0f;
    den += scv;
    const float* __restrict__ vr = vbase + s * F;  // uniform
#pragma unroll
    for (int hh = 0; hh < HD; hh++) acc[hh] += scv * vr[hh];
  }

  // ---- reduce 4 wave-partials per (head, position) -> y in LDS
#pragma unroll
  for (int hh = 0; hh < HD; hh++) red[wave][t][hh] = acc[hh];
  red[wave][t][16] = den;
  __syncthreads();

  for (int idx = threadIdx.x; idx < CHK * DM; idx += 512) {
    int t2 = idx >> 5, c = idx & 31;       // c = h2*16 + hh
    int h2 = c >> 4, hh = c & 15, w0 = h2 * 4;
    float num = red[w0][t2][hh] + red[w0 + 1][t2][hh] + red[w0 + 2][t2][hh] +
                red[w0 + 3][t2][hh];
    float dn = red[w0][t2][16] + red[w0 + 1][t2][16] + red[w0 + 2][t2][16] +
               red[w0 + 3][t2][16];
    ys[t2][c] = num / (dn + 1e-12f);
  }
  __syncthreads();

  // ---- Wo projection: wave handles oc = 4*wave..4*wave+3 (uniform rows)
#pragma unroll
  for (int q = 0; q < 4; q++) {
    int oc = wave * 4 + q;  // uniform
    const float* __restrict__ wr = Wo + (size_t)oc * DM;
    float acc2 = 0.f;
#pragma unroll
    for (int c = 0; c < DM; c++) acc2 += ys[t][c] * wr[c];
    out[((size_t)(b * L + ch * CHK + t)) * DM + oc] = acc2;
  }
}

extern "C" void kernel_launch(void* const* d_in, const int* in_sizes, int n_in,
                              void* d_out, int out_size, void* d_ws,
                              size_t ws_size, hipStream_t stream) {
  const float* hs = (const float*)d_in[0];
  const float* Wq = (const float*)d_in[1];
  const float* Wk = (const float*)d_in[2];
  const float* Wv = (const float*)d_in[3];
  const float* Wo = (const float*)d_in[4];
  float* out = (float*)d_out;

  float* ws = (float*)d_ws;
  float* qp = ws;                                 // BH*L*F      = 262144
  float* kp = qp + (size_t)BH * L * F;            // 262144
  float* vp = kp + (size_t)BH * L * F;            // 262144
  float* S_kv = vp + (size_t)BH * L * F;          // BH*NC*DD*HD = 1118208
  float* S_k = S_kv + (size_t)BH * NC * DD * HD;  // BH*NC*DD    = 69888
  // total ~8 MB fp32 workspace

  chunksum_kernel<<<BH * NC, 256, 0, stream>>>(hs, Wq, Wk, Wv, qp, kp, vp,
                                               S_kv, S_k);
  prefix_kernel<<<BH * PSLICES, 256, 0, stream>>>(S_kv, S_k);
  outchunk_kernel<<<B * NC, 512, 0, stream>>>(qp, kp, vp, S_kv, S_k, Wo, out);
}

// Round 6
// 108.223 us; speedup vs baseline: 1.1027x; 1.1027x over previous
//
#include <hip/hip_runtime.h>
#include <hip/hip_fp16.h>
#include <math.h>

// Problem constants (from reference)
#define B 4
#define H 2
#define L 2048
#define DM 32          // d_model
#define F 16           // feat dim
#define HD 16          // head dim
#define DD 273         // 1 + F + F*F taylor feature dim
#define DDP 280        // padded feature rows (dd = u + 8m, m<35 -> max 279)
#define CHK 64         // chunk length
#define NC (L / CHK)   // 32 chunks
#define BH (B * H)     // 8

#define SC_LIN 0.5f                   // 1/RRD, RRD=2
#define SC_QUAD 0.17677669529663687f  // 1/(RD*sqrt(2)) = 1/(4*sqrt(2))

// ---------------------------------------------------------------------------
// Kernel 1: fused projection + per-chunk state sums.
// Block = (bh, ch), 256 threads. Phase 1: project q,k,v for this chunk's 64
// rows (head h only, 48 channels; lane = row, wave picks 12 channels); write
// q,k,v fp32 to global, keep k fp32 + v f16-packed in LDS.
// Phase 2: thread dd computes S_kv[dd][:], S_k[dd]; v-row broadcast reads are
// half2 (2 x b128 per p instead of 4 -> halves the dominant LDS-pipe cost).
// Rows dd in [DD, DDP) are zero-filled so outchunk's fixed-trip loop is safe.
// ---------------------------------------------------------------------------
__global__ __launch_bounds__(256) void chunksum_kernel(
    const float* __restrict__ hs, const float* __restrict__ Wq,
    const float* __restrict__ Wk, const float* __restrict__ Wv,
    float* __restrict__ qp, float* __restrict__ kp, float* __restrict__ vp,
    float* __restrict__ S_kv, float* __restrict__ S_k) {
  int blk = blockIdx.x;  // bh*NC + ch
  int bh = blk >> 5, ch = blk & (NC - 1);
  int b = bh >> 1, h = bh & 1;
  int lane = threadIdx.x & 63, wave = threadIdx.x >> 6;
  int l = ch * CHK + lane;

  __shared__ float ks[CHK][F + 1];     // fp32, col 16 = 1.0 sentinel
  __shared__ __half vs_h[CHK][F];      // f16-packed v (32B rows)

  // ---- phase 1: projection, x row in registers
  float x[DM];
  const float4* xr = (const float4*)(hs + ((size_t)b * L + l) * DM);
#pragma unroll
  for (int j = 0; j < DM / 4; j++) {
    float4 v = xr[j];
    x[4 * j] = v.x; x[4 * j + 1] = v.y; x[4 * j + 2] = v.z; x[4 * j + 3] = v.w;
  }
  for (int c = wave * 12; c < wave * 12 + 12; c++) {
    int kind = c >> 4;  // 0=q, 1=k, 2=v (uniform per iteration)
    int f = c & 15;
    const float* __restrict__ W = (kind == 0) ? Wq : (kind == 1) ? Wk : Wv;
    const float* wr = W + (size_t)(h * 16 + f) * DM;
    float acc = 0.f;
#pragma unroll
    for (int i = 0; i < DM; i++) acc += x[i] * wr[i];
    float* dst = (kind == 0) ? qp : (kind == 1) ? kp : vp;
    dst[((size_t)bh * L + l) * F + f] = acc;
    if (kind == 1) ks[lane][f] = acc;
    if (kind == 2) vs_h[lane][f] = __float2half(acc);
  }
  if (threadIdx.x < CHK) ks[threadIdx.x][16] = 1.0f;
  __syncthreads();

  // ---- phase 2: per-dd sums
#pragma unroll
  for (int rep = 0; rep < 2; rep++) {
    int dd = threadIdx.x + rep * 256;
    if (dd >= DDP) break;
    float* dst = S_kv + ((size_t)blk * DDP + dd) * HD;
    if (dd >= DD) {  // zero-fill padding rows
#pragma unroll
      for (int hh = 0; hh < HD; hh++) dst[hh] = 0.f;
      S_k[(size_t)blk * DDP + dd] = 0.f;
      continue;
    }
    int i, j;
    float sc;
    if (dd == 0) {
      i = 16; j = 16; sc = 1.0f;
    } else if (dd <= F) {
      i = dd - 1; j = 16; sc = SC_LIN;
    } else {
      int m = dd - 17;
      i = m >> 4; j = m & 15; sc = SC_QUAD;
    }
    float acc[HD];
#pragma unroll
    for (int hh = 0; hh < HD; hh++) acc[hh] = 0.f;
    float acck = 0.f;
    for (int p = 0; p < CHK; p++) {
      float kf = sc * ks[p][i] * ks[p][j];
      acck += kf;
      const __half2* vr = (const __half2*)vs_h[p];  // broadcast (uniform p)
#pragma unroll
      for (int x2 = 0; x2 < 8; x2++) {
        float2 vf = __half22float2(vr[x2]);
        acc[2 * x2] += kf * vf.x;
        acc[2 * x2 + 1] += kf * vf.y;
      }
    }
#pragma unroll
    for (int hh = 0; hh < HD; hh++) dst[hh] = acc[hh];
    S_k[(size_t)blk * DDP + dd] = acck;
  }
}

// ---------------------------------------------------------------------------
// Kernel 2: element-parallel exclusive prefix over NC chunks per (b,h).
// ---------------------------------------------------------------------------
#define PSLICES 19  // ceil((DDP*HD + DDP)/256) = ceil(4760/256)
__global__ __launch_bounds__(256) void prefix_kernel(float* __restrict__ S_kv,
                                                     float* __restrict__ S_k) {
  int blk = blockIdx.x;
  int bh = blk / PSLICES, sl = blk % PSLICES;
  int e = sl * 256 + threadIdx.x;
  if (e < DDP * HD) {
    size_t base = (size_t)bh * NC * DDP * HD + e;
    float v[NC];
#pragma unroll
    for (int c = 0; c < NC; c++) v[c] = S_kv[base + (size_t)c * DDP * HD];
    float run = 0.f;
#pragma unroll
    for (int c = 0; c < NC; c++) {
      S_kv[base + (size_t)c * DDP * HD] = run;
      run += v[c];
    }
  } else if (e < DDP * HD + DDP) {
    int e2 = e - DDP * HD;
    size_t base = (size_t)bh * NC * DDP + e2;
    float v[NC];
#pragma unroll
    for (int c = 0; c < NC; c++) v[c] = S_k[base + (size_t)c * DDP];
    float run = 0.f;
#pragma unroll
    for (int c = 0; c < NC; c++) {
      S_k[base + (size_t)c * DDP] = run;
      run += v[c];
    }
  }
}

// ---------------------------------------------------------------------------
// Kernel 3: per-chunk output. Block = (bh, ch), 512 threads = 8 waves.
// lane = position t; wave u owns dd = u + 8m of the inter sum (FIXED 35-trip
// loop -- state padded to DDP rows so no break; phi zeroed for dd >= DD) and
// s = u + 8m of the intra sum. State/k/v rows are wave-uniform float4 loads;
// LDS holds q (phi operands) and the 8-way reduction buffer.
// ---------------------------------------------------------------------------
__global__ __launch_bounds__(512) void outchunk_kernel(
    const float* __restrict__ qp, const float* __restrict__ kp,
    const float* __restrict__ vp, const float* __restrict__ St_kv,
    const float* __restrict__ St_k, float* __restrict__ y) {
  int blk = blockIdx.x;  // bh*NC + ch
  int bh = blk >> 5, ch = blk & (NC - 1);
  int b = bh >> 1, h = bh & 1;
  int t = threadIdx.x & 63;
  int u = __builtin_amdgcn_readfirstlane(threadIdx.x >> 6);  // 0..7

  __shared__ float qs[CHK][F + 1];   // padded, col 16 = 1.0
  __shared__ float red[8][CHK][21];  // odd stride -> conflict-free

  if (threadIdx.x < 256) {
    const float4* qb =
        (const float4*)(qp + ((size_t)bh * L + (size_t)ch * CHK) * F);
    int r = threadIdx.x >> 2, c4 = (threadIdx.x & 3) * 4;
    float4 v = qb[threadIdx.x];
    qs[r][c4] = v.x; qs[r][c4 + 1] = v.y; qs[r][c4 + 2] = v.z; qs[r][c4 + 3] = v.w;
    if (threadIdx.x < CHK) qs[threadIdx.x][16] = 1.0f;
  }

  float qreg[F];
  const float4* qrow =
      (const float4*)(qp + ((size_t)bh * L + (size_t)ch * CHK + t) * F);
#pragma unroll
  for (int j = 0; j < 4; j++) {
    float4 v = qrow[j];
    qreg[4 * j] = v.x; qreg[4 * j + 1] = v.y;
    qreg[4 * j + 2] = v.z; qreg[4 * j + 3] = v.w;
  }
  __syncthreads();

  float acc[HD];
#pragma unroll
  for (int hh = 0; hh < HD; hh++) acc[hh] = 0.f;
  float den = 0.f;

  const float* __restrict__ Sbase = St_kv + (size_t)blk * DDP * HD;
  const float* __restrict__ Skb = St_k + (size_t)blk * DDP;

  // ---- inter-chunk: dd = u + 8m, FIXED 35 trips (dd max 279 < DDP)
#pragma unroll 5
  for (int m = 0; m < 35; m++) {
    int dd = u + (m << 3);
    float phi;
    if (dd == 0) {
      phi = 1.0f;
    } else if (dd <= F) {
      phi = qs[t][dd - 1] * SC_LIN;
    } else {
      int mm = dd - 17;  // mm>>4 <= 16 -> sentinel col, safe
      phi = qs[t][mm >> 4] * qs[t][mm & 15] * SC_QUAD;
    }
    phi = (dd < DD) ? phi : 0.0f;
    den += phi * Skb[dd];
    const float4* Sr = (const float4*)(Sbase + dd * HD);  // uniform row
    float4 s0 = Sr[0], s1 = Sr[1], s2 = Sr[2], s3 = Sr[3];
    acc[0] += phi * s0.x;  acc[1] += phi * s0.y;
    acc[2] += phi * s0.z;  acc[3] += phi * s0.w;
    acc[4] += phi * s1.x;  acc[5] += phi * s1.y;
    acc[6] += phi * s1.z;  acc[7] += phi * s1.w;
    acc[8] += phi * s2.x;  acc[9] += phi * s2.y;
    acc[10] += phi * s2.z; acc[11] += phi * s2.w;
    acc[12] += phi * s3.x; acc[13] += phi * s3.y;
    acc[14] += phi * s3.z; acc[15] += phi * s3.w;
  }

  // ---- intra-chunk causal: s = u + 8m, closed-form score, masked
  const float* __restrict__ kbase = kp + ((size_t)bh * L + (size_t)ch * CHK) * F;
  const float* __restrict__ vbase = vp + ((size_t)bh * L + (size_t)ch * CHK) * F;
#pragma unroll
  for (int mm = 0; mm < CHK / 8; mm++) {
    int s = u + mm * 8;
    const float4* kr = (const float4*)(kbase + s * F);  // uniform row
    float4 k0 = kr[0], k1 = kr[1], k2 = kr[2], k3 = kr[3];
    float dot = qreg[0] * k0.x + qreg[1] * k0.y + qreg[2] * k0.z +
                qreg[3] * k0.w + qreg[4] * k1.x + qreg[5] * k1.y +
                qreg[6] * k1.z + qreg[7] * k1.w + qreg[8] * k2.x +
                qreg[9] * k2.y + qreg[10] * k2.z + qreg[11] * k2.w +
                qreg[12] * k3.x + qreg[13] * k3.y + qreg[14] * k3.z +
                qreg[15] * k3.w;
    float scv = 1.0f + dot * 0.25f + dot * dot * 0.03125f;
    scv = (s <= t) ? scv : 0.0f;
    den += scv;
    const float4* vr = (const float4*)(vbase + s * F);  // uniform row
    float4 v0 = vr[0], v1 = vr[1], v2 = vr[2], v3 = vr[3];
    acc[0] += scv * v0.x;  acc[1] += scv * v0.y;
    acc[2] += scv * v0.z;  acc[3] += scv * v0.w;
    acc[4] += scv * v1.x;  acc[5] += scv * v1.y;
    acc[6] += scv * v1.z;  acc[7] += scv * v1.w;
    acc[8] += scv * v2.x;  acc[9] += scv * v2.y;
    acc[10] += scv * v2.z; acc[11] += scv * v2.w;
    acc[12] += scv * v3.x; acc[13] += scv * v3.y;
    acc[14] += scv * v3.z; acc[15] += scv * v3.w;
  }

  // ---- 8-way reduction per position
#pragma unroll
  for (int hh = 0; hh < HD; hh++) red[u][t][hh] = acc[hh];
  red[u][t][16] = den;
  __syncthreads();

  for (int idx = threadIdx.x; idx < CHK * 17; idx += 512) {
    int t2 = idx / 17, e = idx % 17;
    float sum = 0.f;
#pragma unroll
    for (int w = 0; w < 8; w++) sum += red[w][t2][e];
    red[0][t2][e] = sum;
  }
  __syncthreads();

  if (threadIdx.x < CHK) {
    int t2 = threadIdx.x;
    float inv = 1.0f / (red[0][t2][16] + 1e-12f);
    float* yb = y + (((size_t)(b * L + ch * CHK + t2)) * H + h) * HD;
#pragma unroll
    for (int hh = 0; hh < HD; hh++) yb[hh] = red[0][t2][hh] * inv;
  }
}

// ---------------------------------------------------------------------------
// Kernel 4: output projection out = y @ Wo^T. Row in regs, uniform Wo rows.
// ---------------------------------------------------------------------------
__global__ __launch_bounds__(256) void out_kernel(const float* __restrict__ y,
                                                  const float* __restrict__ Wo,
                                                  float* __restrict__ out) {
  int lane = threadIdx.x & 63;
  int wave = __builtin_amdgcn_readfirstlane(threadIdx.x >> 6);
  int row = blockIdx.x * 64 + lane;
  float yr[DM];
  const float4* yb = (const float4*)(y + (size_t)row * DM);
#pragma unroll
  for (int j = 0; j < DM / 4; j++) {
    float4 v = yb[j];
    yr[4 * j] = v.x; yr[4 * j + 1] = v.y; yr[4 * j + 2] = v.z; yr[4 * j + 3] = v.w;
  }
  for (int c = wave * 8; c < wave * 8 + 8; c++) {  // uniform
    const float* __restrict__ wr = Wo + (size_t)c * DM;
    float acc = 0.f;
#pragma unroll
    for (int i = 0; i < DM; i++) acc += yr[i] * wr[i];
    out[(size_t)row * DM + c] = acc;
  }
}

extern "C" void kernel_launch(void* const* d_in, const int* in_sizes, int n_in,
                              void* d_out, int out_size, void* d_ws,
                              size_t ws_size, hipStream_t stream) {
  const float* hs = (const float*)d_in[0];
  const float* Wq = (const float*)d_in[1];
  const float* Wk = (const float*)d_in[2];
  const float* Wv = (const float*)d_in[3];
  const float* Wo = (const float*)d_in[4];
  float* out = (float*)d_out;

  float* ws = (float*)d_ws;
  float* qp = ws;                                  // BH*L*F       = 262144
  float* kp = qp + (size_t)BH * L * F;             // 262144
  float* vp = kp + (size_t)BH * L * F;             // 262144
  float* S_kv = vp + (size_t)BH * L * F;           // BH*NC*DDP*HD = 1146880
  float* S_k = S_kv + (size_t)BH * NC * DDP * HD;  // BH*NC*DDP    = 71680
  float* y = S_k + (size_t)BH * NC * DDP;          // B*L*H*HD     = 262144
  // total ~9.3 MB fp32 workspace

  chunksum_kernel<<<BH * NC, 256, 0, stream>>>(hs, Wq, Wk, Wv, qp, kp, vp,
                                               S_kv, S_k);
  prefix_kernel<<<BH * PSLICES, 256, 0, stream>>>(S_kv, S_k);
  outchunk_kernel<<<BH * NC, 512, 0, stream>>>(qp, kp, vp, S_kv, S_k, y);
  out_kernel<<<B * L / 64, 256, 0, stream>>>(y, Wo, out);
}